// Round 14
// baseline (126.382 us; speedup 1.0000x reference)
//
#include <hip/hip_runtime.h>
#include <math.h>

#define NN 50000
#define NE 800000
#define HD 128
#define ED 4
#define NL 4
#define MH 64
#define NE2 400000          // edges per MLP part (edge-split halves)
#define NEH 200000          // threads per MLP part: 2 edges/thread
#define NBIN 196            // bin = dst >> 8 ; 49999>>8 = 195
#define BINCAP 8192         // avg 4082 edges/bin
#define NSTRIDE (NBIN * BINCAP)  // 1605632, kc layer stride (position-indexed)
#define CURSTRIDE 16        // pad cursors to one per 64B line
#define NBF 782             // bin_fill blocks: (NE/4 + 255)/256
#define NMLPE 782           // MLP blocks per part: (NEH + 255)/256

typedef float v2f __attribute__((ext_vector_type(2)));

__device__ __forceinline__ float softplus_f(float a) {
    return fmaxf(a, 0.0f) + __logf(1.0f + __expf(-fabsf(a)));
}

// ---- edge MLP, all 4 layers in one pass, 2 edges/thread, PACKED f32 ----
// v2f pairs the 2 edges per component -> v_pk_fma_f32/v_pk_max_f32.
// j-loop is FULLY unrolled (r14 delta): straight-line body lets the
// scheduler hoist s_load batches far ahead and pipeline K$ latency,
// which r13 showed is the dominant stall (packing halved issue, stall flat).
__device__ __forceinline__ void mlp_all4(
    int part, int t,
    const float* __restrict__ edge_attr,
    const float* __restrict__ ew1, const float* __restrict__ eb1,
    const float* __restrict__ ew2, const float* __restrict__ eb2,
    float4* __restrict__ k4)
{
    if (t >= NEH) return;
    const int e0 = part * NE2 + t;
    const int e1 = e0 + NEH;
    const float4 a0 = *reinterpret_cast<const float4*>(edge_attr + (size_t)e0 * 4);
    const float4 a1 = *reinterpret_cast<const float4*>(edge_attr + (size_t)e1 * 4);

    const v2f ax = {a0.x, a1.x};
    const v2f ay = {a0.y, a1.y};
    const v2f az = {a0.z, a1.z};
    const v2f aw = {a0.w, a1.w};
    const v2f zero = {0.0f, 0.0f};

    float r0[NL], r1[NL];
    #pragma unroll
    for (int l = 0; l < NL; ++l) {
        const float* __restrict__ W0 = ew1 + (size_t)(l * ED + 0) * MH;
        const float* __restrict__ W1 = ew1 + (size_t)(l * ED + 1) * MH;
        const float* __restrict__ W2 = ew1 + (size_t)(l * ED + 2) * MH;
        const float* __restrict__ W3 = ew1 + (size_t)(l * ED + 3) * MH;
        const float* __restrict__ B1 = eb1 + (size_t)l * MH;
        const float* __restrict__ V2 = ew2 + (size_t)l * MH;

        v2f accA = zero, accB = zero;          // 2 independent chains
        #pragma unroll
        for (int j = 0; j < MH; j += 2) {
            {
                const float w0 = W0[j], w1 = W1[j], w2 = W2[j], w3 = W3[j];
                const float b1 = B1[j], v2 = V2[j];
                v2f m = __builtin_elementwise_fma(ax, (v2f){w0, w0},
                        __builtin_elementwise_fma(ay, (v2f){w1, w1},
                        __builtin_elementwise_fma(az, (v2f){w2, w2},
                        __builtin_elementwise_fma(aw, (v2f){w3, w3},
                                                  (v2f){b1, b1}))));
                accA = __builtin_elementwise_fma(
                    __builtin_elementwise_max(m, zero), (v2f){v2, v2}, accA);
            }
            {
                const float w0 = W0[j+1], w1 = W1[j+1], w2 = W2[j+1], w3 = W3[j+1];
                const float b1 = B1[j+1], v2 = V2[j+1];
                v2f m = __builtin_elementwise_fma(ax, (v2f){w0, w0},
                        __builtin_elementwise_fma(ay, (v2f){w1, w1},
                        __builtin_elementwise_fma(az, (v2f){w2, w2},
                        __builtin_elementwise_fma(aw, (v2f){w3, w3},
                                                  (v2f){b1, b1}))));
                accB = __builtin_elementwise_fma(
                    __builtin_elementwise_max(m, zero), (v2f){v2, v2}, accB);
            }
        }
        const float bb = eb2[l];
        v2f acc = accA + accB;
        r0[l] = softplus_f(bb + acc.x);
        r1[l] = softplus_f(bb + acc.y);
    }
    k4[e0] = make_float4(r0[0], r0[1], r0[2], r0[3]);
    k4[e1] = make_float4(r1[0], r1[1], r1[2], r1[3]);
}

// ---------------- dispatch A: bin_fill (blocks 0..NBF-1) || MLP part 0 ---------
__global__ __launch_bounds__(256) void fill_mlpA_kernel(
    const int* __restrict__ eidx,
    int* __restrict__ gcur,          // NBIN*CURSTRIDE ints, pre-zeroed
    int2* __restrict__ gbin,         // NBIN*BINCAP records
    const float* __restrict__ edge_attr,
    const float* __restrict__ ew1, const float* __restrict__ eb1,
    const float* __restrict__ ew2, const float* __restrict__ eb2,
    float4* __restrict__ k4)
{
    __shared__ int hist[NBIN];
    __shared__ int base[NBIN];

    if (blockIdx.x < NBF) {
        // ---- bin_fill: record int2 {src, (dloc<<20)|e}; dloc = dst&255 ----
        int tid = threadIdx.x;
        if (tid < NBIN) hist[tid] = 0;
        __syncthreads();

        int e0 = (blockIdx.x * 256 + tid) * 4;
        int bin[4], dloc[4], rank[4];
        int4 srcs, dsts;
        bool act = e0 < NE;
        if (act) {
            srcs = *reinterpret_cast<const int4*>(eidx + e0);
            dsts = *reinterpret_cast<const int4*>(eidx + NE + e0);
            int dd[4] = {dsts.x, dsts.y, dsts.z, dsts.w};
            #pragma unroll
            for (int i = 0; i < 4; ++i) {
                bin[i]  = dd[i] >> 8;
                dloc[i] = dd[i] & 255;
                rank[i] = atomicAdd(&hist[bin[i]], 1);
            }
        }
        __syncthreads();
        if (tid < NBIN && hist[tid]) base[tid] = atomicAdd(&gcur[tid * CURSTRIDE], hist[tid]);
        __syncthreads();
        if (act) {
            int ss[4] = {srcs.x, srcs.y, srcs.z, srcs.w};
            #pragma unroll
            for (int i = 0; i < 4; ++i) {
                int pos = bin[i] * BINCAP + base[bin[i]] + rank[i];
                gbin[pos] = make_int2(ss[i], (dloc[i] << 20) | (e0 + i));
            }
        }
        return;
    }

    int t = (blockIdx.x - NBF) * 256 + threadIdx.x;
    mlp_all4(0, t, edge_attr, ew1, eb1, ew2, eb2, k4);
}

// ---- dispatch B: csr_build (blocks 0..NBIN-1) || MLP part 1 ----
__global__ __launch_bounds__(256) void csr_mlpB_kernel(
    const int* __restrict__ gcur,
    const int2* __restrict__ gbin,
    int* __restrict__ gs_src,        // src per CSR position
    int* __restrict__ gs_e,          // edge id per CSR position
    int2* __restrict__ nodeSD,       // {start, deg} per node
    const float* __restrict__ edge_attr,
    const float* __restrict__ ew1, const float* __restrict__ eb1,
    const float* __restrict__ ew2, const float* __restrict__ eb2,
    float4* __restrict__ k4)
{
    __shared__ int cnt[256];
    __shared__ int cur[256];
    __shared__ int wsum[4];
    __shared__ int woff[4];

    if (blockIdx.x < NBIN) {
        int b = blockIdx.x;
        int tid = threadIdx.x;
        int lane = tid & 63;
        int wid = tid >> 6;
        int m = gcur[b * CURSTRIDE];
        const int2* src = gbin + (size_t)b * BINCAP;

        cnt[tid] = 0;
        __syncthreads();
        for (int p = tid; p < m; p += 256) {
            int dloc = src[p].y >> 20;
            atomicAdd(&cnt[dloc], 1);
        }
        __syncthreads();
        int v = cnt[tid];
        int xx = v;
        #pragma unroll
        for (int o = 1; o < 64; o <<= 1) {
            int t = __shfl_up(xx, o);
            if (lane >= o) xx += t;
        }
        if (lane == 63) wsum[wid] = xx;
        __syncthreads();
        if (tid == 0) {
            int a = 0;
            #pragma unroll
            for (int w = 0; w < 4; ++w) { woff[w] = a; a += wsum[w]; }
        }
        __syncthreads();
        int excl = xx + woff[wid] - v;
        cur[tid] = excl;
        int n = (b << 8) + tid;
        if (n < NN) nodeSD[n] = make_int2(b * BINCAP + excl, v);
        __syncthreads();
        for (int p = tid; p < m; p += 256) {
            int2 r = src[p];
            int dloc = r.y >> 20;
            int q = atomicAdd(&cur[dloc], 1);
            gs_src[(size_t)b * BINCAP + q] = r.x;
            gs_e  [(size_t)b * BINCAP + q] = r.y & 0xFFFFF;
        }
        return;
    }

    int t = (blockIdx.x - NBIN) * 256 + threadIdx.x;
    mlp_all4(1, t, edge_attr, ew1, eb1, ew2, eb2, k4);
}

// ---- dispatch C: layer-0 gather + k permute into CSR order ----
// Pays the random k4 line fetch ONCE; streams k1..k3 out position-indexed
// so sg1/sg2/sg3 are fully streaming.
__global__ void sg0_kperm_kernel(const int2* __restrict__ nodeSD,
                                 const int* __restrict__ gs_src,
                                 const int* __restrict__ gs_e,
                                 const float4* __restrict__ k4,
                                 const float* __restrict__ x,
                                 float* __restrict__ s_out,
                                 float* __restrict__ kc)   // [3][NSTRIDE]
{
    int t = blockIdx.x * 256 + threadIdx.x;
    int n = t >> 4;
    int gl = threadIdx.x & 15;
    if (n >= NN) return;
    int2 sd = nodeSD[n];
    float sk = 0.0f, sks = 0.0f;
    for (int p = gl; p < sd.y; p += 16) {
        int pos = sd.x + p;
        int e = gs_e[pos];
        int s = gs_src[pos];
        float4 kv = k4[e];
        kc[pos]               = kv.y;
        kc[NSTRIDE + pos]     = kv.z;
        kc[2 * NSTRIDE + pos] = kv.w;
        sk += kv.x;
        sks = fmaf(kv.x, x[s], sks);
    }
    #pragma unroll
    for (int m = 1; m < 16; m <<= 1) {
        sk  += __shfl_xor(sk, m);
        sks += __shfl_xor(sks, m);
    }
    if (gl == 0) s_out[n] = fmaf(-sk, x[n], sks);
}

// ---- dispatches D/E: streaming gather (k already CSR-ordered) ----
__global__ void sg_stream_kernel(const int2* __restrict__ nodeSD,
                                 const int* __restrict__ gs_src,
                                 const float* __restrict__ kcl,  // layer slice
                                 const float* __restrict__ s_in,
                                 float* __restrict__ s_out) {
    int t = blockIdx.x * 256 + threadIdx.x;
    int n = t >> 4;
    int gl = threadIdx.x & 15;
    if (n >= NN) return;
    int2 sd = nodeSD[n];
    float sk = 0.0f, sks = 0.0f;
    for (int p = gl; p < sd.y; p += 16) {
        int pos = sd.x + p;
        float kk = kcl[pos];
        int s = gs_src[pos];
        sk += kk;
        sks = fmaf(kk, s_in[s], sks);
    }
    #pragma unroll
    for (int m = 1; m < 16; m <<= 1) {
        sk  += __shfl_xor(sk, m);
        sks += __shfl_xor(sks, m);
    }
    if (gl == 0) s_out[n] = fmaf(-sk, s_in[n], sks);
}

// ---- dispatch F: streaming layer-3 gather fused with the output head ----
__global__ void sg_head_kernel(const int2* __restrict__ nodeSD,
                               const int* __restrict__ gs_src,
                               const float* __restrict__ kcl,   // k3 slice
                               const float* __restrict__ s_in,
                               const float* __restrict__ ew,
                               const float* __restrict__ ow1,
                               const float* __restrict__ b1,
                               const float* __restrict__ w2,
                               const float* __restrict__ b2,
                               float* __restrict__ out) {
    __shared__ float su[HD], sb1[HD], sw2[HD];
    if (threadIdx.x < HD) {
        int j = threadIdx.x;
        float a = 0.0f;
        #pragma unroll 8
        for (int c = 0; c < HD; ++c) a = fmaf(ew[c], ow1[c * HD + j], a);
        su[j]  = a;
        sb1[j] = b1[j];
        sw2[j] = w2[j];
    }
    __syncthreads();

    int t = blockIdx.x * 256 + threadIdx.x;
    int n = t >> 4;
    int gl = threadIdx.x & 15;
    if (n >= NN) return;
    int2 sd = nodeSD[n];
    float sk = 0.0f, sks = 0.0f;
    for (int p = gl; p < sd.y; p += 16) {
        int pos = sd.x + p;
        float kk = kcl[pos];
        int s = gs_src[pos];
        sk += kk;
        sks = fmaf(kk, s_in[s], sks);
    }
    #pragma unroll
    for (int m = 1; m < 16; m <<= 1) {
        sk  += __shfl_xor(sk, m);
        sks += __shfl_xor(sks, m);
    }
    float sv = fmaf(-sk, s_in[n], sks);   // all 16 lanes hold sv

    float acc = 0.0f;
    #pragma unroll
    for (int jj = 0; jj < 8; ++jj) {
        int j = gl + jj * 16;
        acc = fmaf(fmaxf(fmaf(sv, su[j], sb1[j]), 0.0f), sw2[j], acc);
    }
    #pragma unroll
    for (int m = 1; m < 16; m <<= 1) acc += __shfl_xor(acc, m);
    if (gl == 0) out[n] = acc + b2[0];
}

// ---------------- launch ----------------

extern "C" void kernel_launch(void* const* d_in, const int* in_sizes, int n_in,
                              void* d_out, int out_size, void* d_ws, size_t ws_size,
                              hipStream_t stream) {
    const float* x        = (const float*)d_in[0];
    const int*   eidx     = (const int*)d_in[1];
    const float* edge_attr= (const float*)d_in[2];
    const float* embed_w  = (const float*)d_in[3];
    // d_in[4] = embed_b (cancels in the message; unused)
    const float* ew1      = (const float*)d_in[5];
    const float* eb1      = (const float*)d_in[6];
    const float* ew2      = (const float*)d_in[7];
    const float* eb2      = (const float*)d_in[8];
    const float* ow1      = (const float*)d_in[9];
    const float* ob1      = (const float*)d_in[10];
    const float* ow2      = (const float*)d_in[11];
    const float* ob2      = (const float*)d_in[12];
    float* out = (float*)d_out;

    char* ws = (char*)d_ws;
    const size_t k4bytes = (size_t)NE * sizeof(float4);                // 12.8 MB
    const size_t gbbytes = (size_t)NBIN * BINCAP * sizeof(int2);       // 12.85 MB
    const size_t gsbytes = (size_t)NSTRIDE * sizeof(int);              // 6.42 MB
    const size_t kcbytes = (size_t)3 * NSTRIDE * sizeof(float);        // 19.27 MB
    const size_t curbyte = (size_t)NBIN * CURSTRIDE * sizeof(int);     // 12.5 KB
    const size_t sdbytes = (size_t)NN * sizeof(int2);                  // 400 KB
    const size_t sbytes  = (size_t)NN * sizeof(float);                 // 200 KB

    size_t off = 0;
    float4* k4     = (float4*)(ws + off); off += k4bytes;
    int2*   gbin   = (int2*)  (ws + off); off += gbbytes;
    int*    gs_src = (int*)   (ws + off); off += gsbytes;
    int*    gs_e   = (int*)   (ws + off); off += gsbytes;
    float*  kc     = (float*) (ws + off); off += kcbytes;
    int*    gcur   = (int*)   (ws + off); off += curbyte;
    int2*   nodeSD = (int2*)  (ws + off); off += sdbytes;
    float*  sA     = (float*) (ws + off); off += sbytes;
    float*  sB     = (float*) (ws + off); off += sbytes;

    hipMemsetAsync(gcur, 0, curbyte, stream);

    // A: bin_fill || MLP edges [0, 400k)
    fill_mlpA_kernel<<<NBF + NMLPE, 256, 0, stream>>>(
        eidx, gcur, gbin, edge_attr, ew1, eb1, ew2, eb2, k4);

    // B: csr || MLP edges [400k, 800k)
    csr_mlpB_kernel<<<NBIN + NMLPE, 256, 0, stream>>>(
        gcur, gbin, gs_src, gs_e, nodeSD, edge_attr, ew1, eb1, ew2, eb2, k4);

    const int ggrid = (NN * 16 + 255) / 256;
    // C: layer-0 gather + permute k1..k3 into CSR order
    sg0_kperm_kernel<<<ggrid, 256, 0, stream>>>(
        nodeSD, gs_src, gs_e, k4, x, sA, kc);
    // D: layer-1 gather, streaming
    sg_stream_kernel<<<ggrid, 256, 0, stream>>>(
        nodeSD, gs_src, kc, sA, sB);
    // E: layer-2 gather, streaming
    sg_stream_kernel<<<ggrid, 256, 0, stream>>>(
        nodeSD, gs_src, kc + NSTRIDE, sB, sA);
    // F: layer-3 gather + head, streaming
    sg_head_kernel<<<ggrid, 256, 0, stream>>>(
        nodeSD, gs_src, kc + 2 * (size_t)NSTRIDE, sA,
        embed_w, ow1, ob1, ow2, ob2, out);
}

// Round 15
// 111.563 us; speedup vs baseline: 1.1328x; 1.1328x over previous
//
#include <hip/hip_runtime.h>
#include <math.h>

#define NN 50000
#define NE 800000
#define HD 128
#define ED 4
#define NL 4
#define MH 64
#define NE2 400000          // edges per MLP part (edge-split halves)
#define NEQ 100000          // threads per MLP part: 4 edges/thread
#define NBIN 196            // bin = dst >> 8 ; 49999>>8 = 195
#define BINCAP 8192         // avg 4082 edges/bin
#define NSTRIDE (NBIN * BINCAP)  // 1605632, kc layer stride (position-indexed)
#define CURSTRIDE 16        // pad cursors to one per 64B line
#define NBF 782             // bin_fill blocks: (NE/4 + 255)/256
#define NMLPE 391           // MLP blocks per part: (NEQ + 255)/256

typedef float v2f __attribute__((ext_vector_type(2)));

__device__ __forceinline__ float softplus_f(float a) {
    return fmaxf(a, 0.0f) + __logf(1.0f + __expf(-fabsf(a)));
}

// ---- edge MLP, all 4 layers in one pass, 4 edges/thread, PACKED f32 ----
// Two v2f edge-pairs share every weight broadcast: per j, 12 packed VALU ops
// against the same 6 scalar loads (r13 was 6 ops/6 loads) -> the s_load
// stall fraction halves. j-loop stays unroll-4 (r14 full unroll = I$ blowup).
__device__ __forceinline__ void mlp_all4(
    int part, int t,
    const float* __restrict__ edge_attr,
    const float* __restrict__ ew1, const float* __restrict__ eb1,
    const float* __restrict__ ew2, const float* __restrict__ eb2,
    float4* __restrict__ k4)
{
    if (t >= NEQ) return;
    const int e0 = part * NE2 + t;
    const int e1 = e0 + NEQ;
    const int e2 = e0 + 2 * NEQ;
    const int e3 = e0 + 3 * NEQ;
    const float4 a0 = *reinterpret_cast<const float4*>(edge_attr + (size_t)e0 * 4);
    const float4 a1 = *reinterpret_cast<const float4*>(edge_attr + (size_t)e1 * 4);
    const float4 a2 = *reinterpret_cast<const float4*>(edge_attr + (size_t)e2 * 4);
    const float4 a3 = *reinterpret_cast<const float4*>(edge_attr + (size_t)e3 * 4);

    const v2f axA = {a0.x, a1.x}, axB = {a2.x, a3.x};
    const v2f ayA = {a0.y, a1.y}, ayB = {a2.y, a3.y};
    const v2f azA = {a0.z, a1.z}, azB = {a2.z, a3.z};
    const v2f awA = {a0.w, a1.w}, awB = {a2.w, a3.w};
    const v2f zero = {0.0f, 0.0f};

    float r0[NL], r1[NL], r2[NL], r3[NL];
    #pragma unroll
    for (int l = 0; l < NL; ++l) {
        const float* __restrict__ W0 = ew1 + (size_t)(l * ED + 0) * MH;
        const float* __restrict__ W1 = ew1 + (size_t)(l * ED + 1) * MH;
        const float* __restrict__ W2 = ew1 + (size_t)(l * ED + 2) * MH;
        const float* __restrict__ W3 = ew1 + (size_t)(l * ED + 3) * MH;
        const float* __restrict__ B1 = eb1 + (size_t)l * MH;
        const float* __restrict__ V2 = ew2 + (size_t)l * MH;

        v2f accA = zero, accB = zero;      // edges 0,1: two chains
        v2f accC = zero, accD = zero;      // edges 2,3: two chains
        #pragma unroll 4
        for (int j = 0; j < MH; j += 2) {
            {
                const float w0 = W0[j], w1 = W1[j], w2 = W2[j], w3 = W3[j];
                const float b1 = B1[j], v2 = V2[j];
                const v2f vw0 = {w0, w0}, vw1 = {w1, w1}, vw2 = {w2, w2},
                          vw3 = {w3, w3}, vb1 = {b1, b1}, vv2 = {v2, v2};
                v2f mA = __builtin_elementwise_fma(axA, vw0,
                         __builtin_elementwise_fma(ayA, vw1,
                         __builtin_elementwise_fma(azA, vw2,
                         __builtin_elementwise_fma(awA, vw3, vb1))));
                v2f mB = __builtin_elementwise_fma(axB, vw0,
                         __builtin_elementwise_fma(ayB, vw1,
                         __builtin_elementwise_fma(azB, vw2,
                         __builtin_elementwise_fma(awB, vw3, vb1))));
                accA = __builtin_elementwise_fma(
                    __builtin_elementwise_max(mA, zero), vv2, accA);
                accC = __builtin_elementwise_fma(
                    __builtin_elementwise_max(mB, zero), vv2, accC);
            }
            {
                const float w0 = W0[j+1], w1 = W1[j+1], w2 = W2[j+1], w3 = W3[j+1];
                const float b1 = B1[j+1], v2 = V2[j+1];
                const v2f vw0 = {w0, w0}, vw1 = {w1, w1}, vw2 = {w2, w2},
                          vw3 = {w3, w3}, vb1 = {b1, b1}, vv2 = {v2, v2};
                v2f mA = __builtin_elementwise_fma(axA, vw0,
                         __builtin_elementwise_fma(ayA, vw1,
                         __builtin_elementwise_fma(azA, vw2,
                         __builtin_elementwise_fma(awA, vw3, vb1))));
                v2f mB = __builtin_elementwise_fma(axB, vw0,
                         __builtin_elementwise_fma(ayB, vw1,
                         __builtin_elementwise_fma(azB, vw2,
                         __builtin_elementwise_fma(awB, vw3, vb1))));
                accB = __builtin_elementwise_fma(
                    __builtin_elementwise_max(mA, zero), vv2, accB);
                accD = __builtin_elementwise_fma(
                    __builtin_elementwise_max(mB, zero), vv2, accD);
            }
        }
        const float bb = eb2[l];
        v2f acc01 = accA + accB;
        v2f acc23 = accC + accD;
        r0[l] = softplus_f(bb + acc01.x);
        r1[l] = softplus_f(bb + acc01.y);
        r2[l] = softplus_f(bb + acc23.x);
        r3[l] = softplus_f(bb + acc23.y);
    }
    k4[e0] = make_float4(r0[0], r0[1], r0[2], r0[3]);
    k4[e1] = make_float4(r1[0], r1[1], r1[2], r1[3]);
    k4[e2] = make_float4(r2[0], r2[1], r2[2], r2[3]);
    k4[e3] = make_float4(r3[0], r3[1], r3[2], r3[3]);
}

// ---------------- dispatch A: bin_fill (blocks 0..NBF-1) || MLP part 0 ---------
__global__ __launch_bounds__(256) void fill_mlpA_kernel(
    const int* __restrict__ eidx,
    int* __restrict__ gcur,          // NBIN*CURSTRIDE ints, pre-zeroed
    int2* __restrict__ gbin,         // NBIN*BINCAP records
    const float* __restrict__ edge_attr,
    const float* __restrict__ ew1, const float* __restrict__ eb1,
    const float* __restrict__ ew2, const float* __restrict__ eb2,
    float4* __restrict__ k4)
{
    __shared__ int hist[NBIN];
    __shared__ int base[NBIN];

    if (blockIdx.x < NBF) {
        // ---- bin_fill: record int2 {src, (dloc<<20)|e}; dloc = dst&255 ----
        int tid = threadIdx.x;
        if (tid < NBIN) hist[tid] = 0;
        __syncthreads();

        int e0 = (blockIdx.x * 256 + tid) * 4;
        int bin[4], dloc[4], rank[4];
        int4 srcs, dsts;
        bool act = e0 < NE;
        if (act) {
            srcs = *reinterpret_cast<const int4*>(eidx + e0);
            dsts = *reinterpret_cast<const int4*>(eidx + NE + e0);
            int dd[4] = {dsts.x, dsts.y, dsts.z, dsts.w};
            #pragma unroll
            for (int i = 0; i < 4; ++i) {
                bin[i]  = dd[i] >> 8;
                dloc[i] = dd[i] & 255;
                rank[i] = atomicAdd(&hist[bin[i]], 1);
            }
        }
        __syncthreads();
        if (tid < NBIN && hist[tid]) base[tid] = atomicAdd(&gcur[tid * CURSTRIDE], hist[tid]);
        __syncthreads();
        if (act) {
            int ss[4] = {srcs.x, srcs.y, srcs.z, srcs.w};
            #pragma unroll
            for (int i = 0; i < 4; ++i) {
                int pos = bin[i] * BINCAP + base[bin[i]] + rank[i];
                gbin[pos] = make_int2(ss[i], (dloc[i] << 20) | (e0 + i));
            }
        }
        return;
    }

    int t = (blockIdx.x - NBF) * 256 + threadIdx.x;
    mlp_all4(0, t, edge_attr, ew1, eb1, ew2, eb2, k4);
}

// ---- dispatch B: csr_build (blocks 0..NBIN-1) || MLP part 1 ----
__global__ __launch_bounds__(256) void csr_mlpB_kernel(
    const int* __restrict__ gcur,
    const int2* __restrict__ gbin,
    int* __restrict__ gs_src,        // src per CSR position
    int* __restrict__ gs_e,          // edge id per CSR position
    int2* __restrict__ nodeSD,       // {start, deg} per node
    const float* __restrict__ edge_attr,
    const float* __restrict__ ew1, const float* __restrict__ eb1,
    const float* __restrict__ ew2, const float* __restrict__ eb2,
    float4* __restrict__ k4)
{
    __shared__ int cnt[256];
    __shared__ int cur[256];
    __shared__ int wsum[4];
    __shared__ int woff[4];

    if (blockIdx.x < NBIN) {
        int b = blockIdx.x;
        int tid = threadIdx.x;
        int lane = tid & 63;
        int wid = tid >> 6;
        int m = gcur[b * CURSTRIDE];
        const int2* src = gbin + (size_t)b * BINCAP;

        cnt[tid] = 0;
        __syncthreads();
        for (int p = tid; p < m; p += 256) {
            int dloc = src[p].y >> 20;
            atomicAdd(&cnt[dloc], 1);
        }
        __syncthreads();
        int v = cnt[tid];
        int xx = v;
        #pragma unroll
        for (int o = 1; o < 64; o <<= 1) {
            int t = __shfl_up(xx, o);
            if (lane >= o) xx += t;
        }
        if (lane == 63) wsum[wid] = xx;
        __syncthreads();
        if (tid == 0) {
            int a = 0;
            #pragma unroll
            for (int w = 0; w < 4; ++w) { woff[w] = a; a += wsum[w]; }
        }
        __syncthreads();
        int excl = xx + woff[wid] - v;
        cur[tid] = excl;
        int n = (b << 8) + tid;
        if (n < NN) nodeSD[n] = make_int2(b * BINCAP + excl, v);
        __syncthreads();
        for (int p = tid; p < m; p += 256) {
            int2 r = src[p];
            int dloc = r.y >> 20;
            int q = atomicAdd(&cur[dloc], 1);
            gs_src[(size_t)b * BINCAP + q] = r.x;
            gs_e  [(size_t)b * BINCAP + q] = r.y & 0xFFFFF;
        }
        return;
    }

    int t = (blockIdx.x - NBIN) * 256 + threadIdx.x;
    mlp_all4(1, t, edge_attr, ew1, eb1, ew2, eb2, k4);
}

// ---- dispatch C: layer-0 gather + k permute into CSR order ----
// Pays the random k4 line fetch ONCE; streams k1..k3 out position-indexed
// so sg1/sg2/sg3 are fully streaming.
__global__ void sg0_kperm_kernel(const int2* __restrict__ nodeSD,
                                 const int* __restrict__ gs_src,
                                 const int* __restrict__ gs_e,
                                 const float4* __restrict__ k4,
                                 const float* __restrict__ x,
                                 float* __restrict__ s_out,
                                 float* __restrict__ kc)   // [3][NSTRIDE]
{
    int t = blockIdx.x * 256 + threadIdx.x;
    int n = t >> 4;
    int gl = threadIdx.x & 15;
    if (n >= NN) return;
    int2 sd = nodeSD[n];
    float sk = 0.0f, sks = 0.0f;
    for (int p = gl; p < sd.y; p += 16) {
        int pos = sd.x + p;
        int e = gs_e[pos];
        int s = gs_src[pos];
        float4 kv = k4[e];
        kc[pos]               = kv.y;
        kc[NSTRIDE + pos]     = kv.z;
        kc[2 * NSTRIDE + pos] = kv.w;
        sk += kv.x;
        sks = fmaf(kv.x, x[s], sks);
    }
    #pragma unroll
    for (int m = 1; m < 16; m <<= 1) {
        sk  += __shfl_xor(sk, m);
        sks += __shfl_xor(sks, m);
    }
    if (gl == 0) s_out[n] = fmaf(-sk, x[n], sks);
}

// ---- dispatches D/E: streaming gather (k already CSR-ordered) ----
__global__ void sg_stream_kernel(const int2* __restrict__ nodeSD,
                                 const int* __restrict__ gs_src,
                                 const float* __restrict__ kcl,  // layer slice
                                 const float* __restrict__ s_in,
                                 float* __restrict__ s_out) {
    int t = blockIdx.x * 256 + threadIdx.x;
    int n = t >> 4;
    int gl = threadIdx.x & 15;
    if (n >= NN) return;
    int2 sd = nodeSD[n];
    float sk = 0.0f, sks = 0.0f;
    for (int p = gl; p < sd.y; p += 16) {
        int pos = sd.x + p;
        float kk = kcl[pos];
        int s = gs_src[pos];
        sk += kk;
        sks = fmaf(kk, s_in[s], sks);
    }
    #pragma unroll
    for (int m = 1; m < 16; m <<= 1) {
        sk  += __shfl_xor(sk, m);
        sks += __shfl_xor(sks, m);
    }
    if (gl == 0) s_out[n] = fmaf(-sk, s_in[n], sks);
}

// ---- dispatch F: streaming layer-3 gather fused with the output head ----
__global__ void sg_head_kernel(const int2* __restrict__ nodeSD,
                               const int* __restrict__ gs_src,
                               const float* __restrict__ kcl,   // k3 slice
                               const float* __restrict__ s_in,
                               const float* __restrict__ ew,
                               const float* __restrict__ ow1,
                               const float* __restrict__ b1,
                               const float* __restrict__ w2,
                               const float* __restrict__ b2,
                               float* __restrict__ out) {
    __shared__ float su[HD], sb1[HD], sw2[HD];
    if (threadIdx.x < HD) {
        int j = threadIdx.x;
        float a = 0.0f;
        #pragma unroll 8
        for (int c = 0; c < HD; ++c) a = fmaf(ew[c], ow1[c * HD + j], a);
        su[j]  = a;
        sb1[j] = b1[j];
        sw2[j] = w2[j];
    }
    __syncthreads();

    int t = blockIdx.x * 256 + threadIdx.x;
    int n = t >> 4;
    int gl = threadIdx.x & 15;
    if (n >= NN) return;
    int2 sd = nodeSD[n];
    float sk = 0.0f, sks = 0.0f;
    for (int p = gl; p < sd.y; p += 16) {
        int pos = sd.x + p;
        float kk = kcl[pos];
        int s = gs_src[pos];
        sk += kk;
        sks = fmaf(kk, s_in[s], sks);
    }
    #pragma unroll
    for (int m = 1; m < 16; m <<= 1) {
        sk  += __shfl_xor(sk, m);
        sks += __shfl_xor(sks, m);
    }
    float sv = fmaf(-sk, s_in[n], sks);   // all 16 lanes hold sv

    float acc = 0.0f;
    #pragma unroll
    for (int jj = 0; jj < 8; ++jj) {
        int j = gl + jj * 16;
        acc = fmaf(fmaxf(fmaf(sv, su[j], sb1[j]), 0.0f), sw2[j], acc);
    }
    #pragma unroll
    for (int m = 1; m < 16; m <<= 1) acc += __shfl_xor(acc, m);
    if (gl == 0) out[n] = acc + b2[0];
}

// ---------------- launch ----------------

extern "C" void kernel_launch(void* const* d_in, const int* in_sizes, int n_in,
                              void* d_out, int out_size, void* d_ws, size_t ws_size,
                              hipStream_t stream) {
    const float* x        = (const float*)d_in[0];
    const int*   eidx     = (const int*)d_in[1];
    const float* edge_attr= (const float*)d_in[2];
    const float* embed_w  = (const float*)d_in[3];
    // d_in[4] = embed_b (cancels in the message; unused)
    const float* ew1      = (const float*)d_in[5];
    const float* eb1      = (const float*)d_in[6];
    const float* ew2      = (const float*)d_in[7];
    const float* eb2      = (const float*)d_in[8];
    const float* ow1      = (const float*)d_in[9];
    const float* ob1      = (const float*)d_in[10];
    const float* ow2      = (const float*)d_in[11];
    const float* ob2      = (const float*)d_in[12];
    float* out = (float*)d_out;

    char* ws = (char*)d_ws;
    const size_t k4bytes = (size_t)NE * sizeof(float4);                // 12.8 MB
    const size_t gbbytes = (size_t)NBIN * BINCAP * sizeof(int2);       // 12.85 MB
    const size_t gsbytes = (size_t)NSTRIDE * sizeof(int);              // 6.42 MB
    const size_t kcbytes = (size_t)3 * NSTRIDE * sizeof(float);        // 19.27 MB
    const size_t curbyte = (size_t)NBIN * CURSTRIDE * sizeof(int);     // 12.5 KB
    const size_t sdbytes = (size_t)NN * sizeof(int2);                  // 400 KB
    const size_t sbytes  = (size_t)NN * sizeof(float);                 // 200 KB

    size_t off = 0;
    float4* k4     = (float4*)(ws + off); off += k4bytes;
    int2*   gbin   = (int2*)  (ws + off); off += gbbytes;
    int*    gs_src = (int*)   (ws + off); off += gsbytes;
    int*    gs_e   = (int*)   (ws + off); off += gsbytes;
    float*  kc     = (float*) (ws + off); off += kcbytes;
    int*    gcur   = (int*)   (ws + off); off += curbyte;
    int2*   nodeSD = (int2*)  (ws + off); off += sdbytes;
    float*  sA     = (float*) (ws + off); off += sbytes;
    float*  sB     = (float*) (ws + off); off += sbytes;

    hipMemsetAsync(gcur, 0, curbyte, stream);

    // A: bin_fill || MLP edges [0, 400k)
    fill_mlpA_kernel<<<NBF + NMLPE, 256, 0, stream>>>(
        eidx, gcur, gbin, edge_attr, ew1, eb1, ew2, eb2, k4);

    // B: csr || MLP edges [400k, 800k)
    csr_mlpB_kernel<<<NBIN + NMLPE, 256, 0, stream>>>(
        gcur, gbin, gs_src, gs_e, nodeSD, edge_attr, ew1, eb1, ew2, eb2, k4);

    const int ggrid = (NN * 16 + 255) / 256;
    // C: layer-0 gather + permute k1..k3 into CSR order
    sg0_kperm_kernel<<<ggrid, 256, 0, stream>>>(
        nodeSD, gs_src, gs_e, k4, x, sA, kc);
    // D: layer-1 gather, streaming
    sg_stream_kernel<<<ggrid, 256, 0, stream>>>(
        nodeSD, gs_src, kc, sA, sB);
    // E: layer-2 gather, streaming
    sg_stream_kernel<<<ggrid, 256, 0, stream>>>(
        nodeSD, gs_src, kc + NSTRIDE, sB, sA);
    // F: layer-3 gather + head, streaming
    sg_head_kernel<<<ggrid, 256, 0, stream>>>(
        nodeSD, gs_src, kc + 2 * (size_t)NSTRIDE, sA,
        embed_w, ow1, ob1, ow2, ob2, out);
}

// Round 16
// 108.051 us; speedup vs baseline: 1.1697x; 1.0325x over previous
//
#include <hip/hip_runtime.h>
#include <math.h>

#define NN 50000
#define NE 800000
#define HD 128
#define ED 4
#define NL 4
#define MH 64
#define NE2 400000          // edges per MLP part (edge-split halves)
#define NEH 200000          // threads per MLP part: 2 edges/thread (r13 proven)
#define NBIN 196            // bin = dst >> 8 ; 49999>>8 = 195
#define BINCAP 8192         // avg 4082 edges/bin
#define NSTRIDE (NBIN * BINCAP)  // 1605632, kc layer stride (position-indexed)
#define CURSTRIDE 16        // pad cursors to one per 64B line
#define NBF 782             // bin_fill blocks: (NE/4 + 255)/256
#define NMLPE 782           // MLP blocks per part: (NEH + 255)/256

typedef float v2f __attribute__((ext_vector_type(2)));

__device__ __forceinline__ float softplus_f(float a) {
    return fmaxf(a, 0.0f) + __logf(1.0f + __expf(-fabsf(a)));
}

// ---- edge MLP, all 4 layers in one pass, 2 edges/thread, PACKED f32 ----
// (r13 champion form: v_pk_fma_f32/v_pk_max_f32, unroll-4 j-loop.)
__device__ __forceinline__ void mlp_all4(
    int part, int t,
    const float* __restrict__ edge_attr,
    const float* __restrict__ ew1, const float* __restrict__ eb1,
    const float* __restrict__ ew2, const float* __restrict__ eb2,
    float4* __restrict__ k4)
{
    if (t >= NEH) return;
    const int e0 = part * NE2 + t;
    const int e1 = e0 + NEH;
    const float4 a0 = *reinterpret_cast<const float4*>(edge_attr + (size_t)e0 * 4);
    const float4 a1 = *reinterpret_cast<const float4*>(edge_attr + (size_t)e1 * 4);

    const v2f ax = {a0.x, a1.x};
    const v2f ay = {a0.y, a1.y};
    const v2f az = {a0.z, a1.z};
    const v2f aw = {a0.w, a1.w};
    const v2f zero = {0.0f, 0.0f};

    float r0[NL], r1[NL];
    #pragma unroll
    for (int l = 0; l < NL; ++l) {
        const float* __restrict__ W0 = ew1 + (size_t)(l * ED + 0) * MH;
        const float* __restrict__ W1 = ew1 + (size_t)(l * ED + 1) * MH;
        const float* __restrict__ W2 = ew1 + (size_t)(l * ED + 2) * MH;
        const float* __restrict__ W3 = ew1 + (size_t)(l * ED + 3) * MH;
        const float* __restrict__ B1 = eb1 + (size_t)l * MH;
        const float* __restrict__ V2 = ew2 + (size_t)l * MH;

        v2f accA = zero, accB = zero;          // 2 independent chains
        #pragma unroll 4
        for (int j = 0; j < MH; j += 2) {
            {
                const float w0 = W0[j], w1 = W1[j], w2 = W2[j], w3 = W3[j];
                const float b1 = B1[j], v2 = V2[j];
                v2f m = __builtin_elementwise_fma(ax, (v2f){w0, w0},
                        __builtin_elementwise_fma(ay, (v2f){w1, w1},
                        __builtin_elementwise_fma(az, (v2f){w2, w2},
                        __builtin_elementwise_fma(aw, (v2f){w3, w3},
                                                  (v2f){b1, b1}))));
                accA = __builtin_elementwise_fma(
                    __builtin_elementwise_max(m, zero), (v2f){v2, v2}, accA);
            }
            {
                const float w0 = W0[j+1], w1 = W1[j+1], w2 = W2[j+1], w3 = W3[j+1];
                const float b1 = B1[j+1], v2 = V2[j+1];
                v2f m = __builtin_elementwise_fma(ax, (v2f){w0, w0},
                        __builtin_elementwise_fma(ay, (v2f){w1, w1},
                        __builtin_elementwise_fma(az, (v2f){w2, w2},
                        __builtin_elementwise_fma(aw, (v2f){w3, w3},
                                                  (v2f){b1, b1}))));
                accB = __builtin_elementwise_fma(
                    __builtin_elementwise_max(m, zero), (v2f){v2, v2}, accB);
            }
        }
        const float bb = eb2[l];
        v2f acc = accA + accB;
        r0[l] = softplus_f(bb + acc.x);
        r1[l] = softplus_f(bb + acc.y);
    }
    k4[e0] = make_float4(r0[0], r0[1], r0[2], r0[3]);
    k4[e1] = make_float4(r1[0], r1[1], r1[2], r1[3]);
}

// ---------------- dispatch A: bin_fill (blocks 0..NBF-1) || MLP part 0 ---------
__global__ __launch_bounds__(256) void fill_mlpA_kernel(
    const int* __restrict__ eidx,
    int* __restrict__ gcur,          // NBIN*CURSTRIDE ints, pre-zeroed
    int2* __restrict__ gbin,         // NBIN*BINCAP records
    const float* __restrict__ edge_attr,
    const float* __restrict__ ew1, const float* __restrict__ eb1,
    const float* __restrict__ ew2, const float* __restrict__ eb2,
    float4* __restrict__ k4)
{
    __shared__ int hist[NBIN];
    __shared__ int base[NBIN];

    if (blockIdx.x < NBF) {
        // ---- bin_fill: record int2 {src, (dloc<<20)|e}; dloc = dst&255 ----
        int tid = threadIdx.x;
        if (tid < NBIN) hist[tid] = 0;
        __syncthreads();

        int e0 = (blockIdx.x * 256 + tid) * 4;
        int bin[4], dloc[4], rank[4];
        int4 srcs, dsts;
        bool act = e0 < NE;
        if (act) {
            srcs = *reinterpret_cast<const int4*>(eidx + e0);
            dsts = *reinterpret_cast<const int4*>(eidx + NE + e0);
            int dd[4] = {dsts.x, dsts.y, dsts.z, dsts.w};
            #pragma unroll
            for (int i = 0; i < 4; ++i) {
                bin[i]  = dd[i] >> 8;
                dloc[i] = dd[i] & 255;
                rank[i] = atomicAdd(&hist[bin[i]], 1);
            }
        }
        __syncthreads();
        if (tid < NBIN && hist[tid]) base[tid] = atomicAdd(&gcur[tid * CURSTRIDE], hist[tid]);
        __syncthreads();
        if (act) {
            int ss[4] = {srcs.x, srcs.y, srcs.z, srcs.w};
            #pragma unroll
            for (int i = 0; i < 4; ++i) {
                int pos = bin[i] * BINCAP + base[bin[i]] + rank[i];
                gbin[pos] = make_int2(ss[i], (dloc[i] << 20) | (e0 + i));
            }
        }
        return;
    }

    int t = (blockIdx.x - NBF) * 256 + threadIdx.x;
    mlp_all4(0, t, edge_attr, ew1, eb1, ew2, eb2, k4);
}

// ---- dispatch B: csr_build (blocks 0..NBIN-1) || MLP part 1 ----
__global__ __launch_bounds__(256) void csr_mlpB_kernel(
    const int* __restrict__ gcur,
    const int2* __restrict__ gbin,
    unsigned short* __restrict__ gs_src,  // src per CSR position (src < 2^16)
    int* __restrict__ gs_e,               // edge id per CSR position
    int2* __restrict__ nodeSD,            // {start, deg} per node
    const float* __restrict__ edge_attr,
    const float* __restrict__ ew1, const float* __restrict__ eb1,
    const float* __restrict__ ew2, const float* __restrict__ eb2,
    float4* __restrict__ k4)
{
    __shared__ int cnt[256];
    __shared__ int cur[256];
    __shared__ int wsum[4];
    __shared__ int woff[4];

    if (blockIdx.x < NBIN) {
        int b = blockIdx.x;
        int tid = threadIdx.x;
        int lane = tid & 63;
        int wid = tid >> 6;
        int m = gcur[b * CURSTRIDE];
        const int2* src = gbin + (size_t)b * BINCAP;

        cnt[tid] = 0;
        __syncthreads();
        for (int p = tid; p < m; p += 256) {
            int dloc = src[p].y >> 20;
            atomicAdd(&cnt[dloc], 1);
        }
        __syncthreads();
        int v = cnt[tid];
        int xx = v;
        #pragma unroll
        for (int o = 1; o < 64; o <<= 1) {
            int t = __shfl_up(xx, o);
            if (lane >= o) xx += t;
        }
        if (lane == 63) wsum[wid] = xx;
        __syncthreads();
        if (tid == 0) {
            int a = 0;
            #pragma unroll
            for (int w = 0; w < 4; ++w) { woff[w] = a; a += wsum[w]; }
        }
        __syncthreads();
        int excl = xx + woff[wid] - v;
        cur[tid] = excl;
        int n = (b << 8) + tid;
        if (n < NN) nodeSD[n] = make_int2(b * BINCAP + excl, v);
        __syncthreads();
        for (int p = tid; p < m; p += 256) {
            int2 r = src[p];
            int dloc = r.y >> 20;
            int q = atomicAdd(&cur[dloc], 1);
            gs_src[(size_t)b * BINCAP + q] = (unsigned short)r.x;
            gs_e  [(size_t)b * BINCAP + q] = r.y & 0xFFFFF;
        }
        return;
    }

    int t = (blockIdx.x - NBIN) * 256 + threadIdx.x;
    mlp_all4(1, t, edge_attr, ew1, eb1, ew2, eb2, k4);
}

// ---- dispatch C: layer-0 gather + k permute into CSR order ----
// Pays the random k4 line fetch ONCE; streams k1..k3 out position-indexed
// so sg1/sg2/sg3 are fully streaming.
__global__ void sg0_kperm_kernel(const int2* __restrict__ nodeSD,
                                 const unsigned short* __restrict__ gs_src,
                                 const int* __restrict__ gs_e,
                                 const float4* __restrict__ k4,
                                 const float* __restrict__ x,
                                 float* __restrict__ s_out,
                                 float* __restrict__ kc)   // [3][NSTRIDE]
{
    int t = blockIdx.x * 256 + threadIdx.x;
    int n = t >> 4;
    int gl = threadIdx.x & 15;
    if (n >= NN) return;
    int2 sd = nodeSD[n];
    float sk = 0.0f, sks = 0.0f;
    for (int p = gl; p < sd.y; p += 16) {
        int pos = sd.x + p;
        int e = gs_e[pos];
        int s = gs_src[pos];
        float4 kv = k4[e];
        kc[pos]               = kv.y;
        kc[NSTRIDE + pos]     = kv.z;
        kc[2 * NSTRIDE + pos] = kv.w;
        sk += kv.x;
        sks = fmaf(kv.x, x[s], sks);
    }
    #pragma unroll
    for (int m = 1; m < 16; m <<= 1) {
        sk  += __shfl_xor(sk, m);
        sks += __shfl_xor(sks, m);
    }
    if (gl == 0) s_out[n] = fmaf(-sk, x[n], sks);
}

// ---- dispatches D/E: streaming gather (k already CSR-ordered) ----
__global__ void sg_stream_kernel(const int2* __restrict__ nodeSD,
                                 const unsigned short* __restrict__ gs_src,
                                 const float* __restrict__ kcl,  // layer slice
                                 const float* __restrict__ s_in,
                                 float* __restrict__ s_out) {
    int t = blockIdx.x * 256 + threadIdx.x;
    int n = t >> 4;
    int gl = threadIdx.x & 15;
    if (n >= NN) return;
    int2 sd = nodeSD[n];
    float sk = 0.0f, sks = 0.0f;
    for (int p = gl; p < sd.y; p += 16) {
        int pos = sd.x + p;
        float kk = kcl[pos];
        int s = gs_src[pos];
        sk += kk;
        sks = fmaf(kk, s_in[s], sks);
    }
    #pragma unroll
    for (int m = 1; m < 16; m <<= 1) {
        sk  += __shfl_xor(sk, m);
        sks += __shfl_xor(sks, m);
    }
    if (gl == 0) s_out[n] = fmaf(-sk, s_in[n], sks);
}

// ---- dispatch F: streaming layer-3 gather fused with the output head ----
__global__ void sg_head_kernel(const int2* __restrict__ nodeSD,
                               const unsigned short* __restrict__ gs_src,
                               const float* __restrict__ kcl,   // k3 slice
                               const float* __restrict__ s_in,
                               const float* __restrict__ ew,
                               const float* __restrict__ ow1,
                               const float* __restrict__ b1,
                               const float* __restrict__ w2,
                               const float* __restrict__ b2,
                               float* __restrict__ out) {
    __shared__ float su[HD], sb1[HD], sw2[HD];
    if (threadIdx.x < HD) {
        int j = threadIdx.x;
        float a = 0.0f;
        #pragma unroll 8
        for (int c = 0; c < HD; ++c) a = fmaf(ew[c], ow1[c * HD + j], a);
        su[j]  = a;
        sb1[j] = b1[j];
        sw2[j] = w2[j];
    }
    __syncthreads();

    int t = blockIdx.x * 256 + threadIdx.x;
    int n = t >> 4;
    int gl = threadIdx.x & 15;
    if (n >= NN) return;
    int2 sd = nodeSD[n];
    float sk = 0.0f, sks = 0.0f;
    for (int p = gl; p < sd.y; p += 16) {
        int pos = sd.x + p;
        float kk = kcl[pos];
        int s = gs_src[pos];
        sk += kk;
        sks = fmaf(kk, s_in[s], sks);
    }
    #pragma unroll
    for (int m = 1; m < 16; m <<= 1) {
        sk  += __shfl_xor(sk, m);
        sks += __shfl_xor(sks, m);
    }
    float sv = fmaf(-sk, s_in[n], sks);   // all 16 lanes hold sv

    float acc = 0.0f;
    #pragma unroll
    for (int jj = 0; jj < 8; ++jj) {
        int j = gl + jj * 16;
        acc = fmaf(fmaxf(fmaf(sv, su[j], sb1[j]), 0.0f), sw2[j], acc);
    }
    #pragma unroll
    for (int m = 1; m < 16; m <<= 1) acc += __shfl_xor(acc, m);
    if (gl == 0) out[n] = acc + b2[0];
}

// ---------------- launch ----------------

extern "C" void kernel_launch(void* const* d_in, const int* in_sizes, int n_in,
                              void* d_out, int out_size, void* d_ws, size_t ws_size,
                              hipStream_t stream) {
    const float* x        = (const float*)d_in[0];
    const int*   eidx     = (const int*)d_in[1];
    const float* edge_attr= (const float*)d_in[2];
    const float* embed_w  = (const float*)d_in[3];
    // d_in[4] = embed_b (cancels in the message; unused)
    const float* ew1      = (const float*)d_in[5];
    const float* eb1      = (const float*)d_in[6];
    const float* ew2      = (const float*)d_in[7];
    const float* eb2      = (const float*)d_in[8];
    const float* ow1      = (const float*)d_in[9];
    const float* ob1      = (const float*)d_in[10];
    const float* ow2      = (const float*)d_in[11];
    const float* ob2      = (const float*)d_in[12];
    float* out = (float*)d_out;

    char* ws = (char*)d_ws;
    const size_t k4bytes = (size_t)NE * sizeof(float4);                   // 12.8 MB
    const size_t gbbytes = (size_t)NBIN * BINCAP * sizeof(int2);          // 12.85 MB
    const size_t gsbytes = (size_t)NSTRIDE * sizeof(unsigned short);      // 3.21 MB
    const size_t gebytes = (size_t)NSTRIDE * sizeof(int);                 // 6.42 MB
    const size_t kcbytes = (size_t)3 * NSTRIDE * sizeof(float);           // 19.27 MB
    const size_t curbyte = (size_t)NBIN * CURSTRIDE * sizeof(int);        // 12.5 KB
    const size_t sdbytes = (size_t)NN * sizeof(int2);                     // 400 KB
    const size_t sbytes  = (size_t)NN * sizeof(float);                    // 200 KB

    size_t off = 0;
    float4* k4              = (float4*)(ws + off); off += k4bytes;
    int2*   gbin            = (int2*)  (ws + off); off += gbbytes;
    unsigned short* gs_src  = (unsigned short*)(ws + off); off += gsbytes;
    off = (off + 3) & ~(size_t)3;   // realign to 4B
    int*    gs_e   = (int*)   (ws + off); off += gebytes;
    float*  kc     = (float*) (ws + off); off += kcbytes;
    int*    gcur   = (int*)   (ws + off); off += curbyte;
    int2*   nodeSD = (int2*)  (ws + off); off += sdbytes;
    float*  sA     = (float*) (ws + off); off += sbytes;
    float*  sB     = (float*) (ws + off); off += sbytes;

    hipMemsetAsync(gcur, 0, curbyte, stream);

    // A: bin_fill || MLP edges [0, 400k)
    fill_mlpA_kernel<<<NBF + NMLPE, 256, 0, stream>>>(
        eidx, gcur, gbin, edge_attr, ew1, eb1, ew2, eb2, k4);

    // B: csr || MLP edges [400k, 800k)
    csr_mlpB_kernel<<<NBIN + NMLPE, 256, 0, stream>>>(
        gcur, gbin, gs_src, gs_e, nodeSD, edge_attr, ew1, eb1, ew2, eb2, k4);

    const int ggrid = (NN * 16 + 255) / 256;
    // C: layer-0 gather + permute k1..k3 into CSR order
    sg0_kperm_kernel<<<ggrid, 256, 0, stream>>>(
        nodeSD, gs_src, gs_e, k4, x, sA, kc);
    // D: layer-1 gather, streaming
    sg_stream_kernel<<<ggrid, 256, 0, stream>>>(
        nodeSD, gs_src, kc, sA, sB);
    // E: layer-2 gather, streaming
    sg_stream_kernel<<<ggrid, 256, 0, stream>>>(
        nodeSD, gs_src, kc + NSTRIDE, sB, sA);
    // F: layer-3 gather + head, streaming
    sg_head_kernel<<<ggrid, 256, 0, stream>>>(
        nodeSD, gs_src, kc + 2 * (size_t)NSTRIDE, sA,
        embed_w, ow1, ob1, ow2, ob2, out);
}